// Round 13
// baseline (84.488 us; speedup 1.0000x reference)
//
#include <hip/hip_runtime.h>
#include <hip/hip_bf16.h>
#include <math.h>

#define LEN_M   131328
#define D_P1    513
#define NROW    4096
#define PRED_ELEMS (NROW * 64)            // 262144

// ws: wcbt bf16, 512 KB: 8 k-chunks (kc) of 64 KB; each holds all 512 cols x
// 64 k as 16B chunks, swizzled: chunk_idx(c, g, kc) = kc*4096 + c*8 + (g^(c&7))
typedef __attribute__((ext_vector_type(8))) short short8;     // 8 bf16 = 4 VGPR
typedef __attribute__((ext_vector_type(4))) float floatx4;    // mfma acc
typedef __attribute__((ext_vector_type(2))) float v2f;        // packed fp32

__device__ __forceinline__ void gl_lds16(const void* g, void* l)
{
    __builtin_amdgcn_global_load_lds(
        (const __attribute__((address_space(1))) unsigned int*)g,
        (__attribute__((address_space(3))) unsigned int*)l, 16, 0, 0);
}

__device__ __forceinline__ unsigned short bf16b(float f)
{
    __hip_bfloat16 h = __float2bfloat16(f);
    return *(unsigned short*)&h;
}

// ------------------------------------------------------------------ prep ----
// blocks [0,513): m_w0 / v_w0 outputs (513*256 == LEN_M exactly)
// blocks [513,769): zero pred region (atomic accumulation base)
// blocks [769,833): build swizzled wcbt via LDS transpose
__global__ __launch_bounds__(256) void prep_kernel(
    const float* __restrict__ params, float* __restrict__ out,
    __hip_bfloat16* __restrict__ wcbt)
{
    __shared__ unsigned short T[64][65];
    const int bid = blockIdx.x;
    const int t   = threadIdx.x;

    if (bid < 513) {
        int i = bid * 256 + t;
        float m = params[i];
        float v = fmaxf(params[LEN_M + i], 0.0f) + 1e-6f;
        out[PRED_ELEMS + i]         = m;                 // m_w0
        out[PRED_ELEMS + LEN_M + i] = v;                 // v_w0
        return;
    }
    if (bid < 769) {
        int i = (bid - 513) * 1024 + t * 4;
        float4 z = {0.f, 0.f, 0.f, 0.f};
        *(float4*)(out + i) = z;
        return;
    }

    const int b2 = bid - 769;
    const int k0 = (b2 & 7) * 64;
    const int c0 = (b2 >> 3) * 64;
    const int hh = t & 63, kb = t >> 6;
    const bool spart = (c0 >= 256);
    const int hbase = c0 & 255;
    const float* src = params + (spart ? LEN_M : 0);

    #pragma unroll 4
    for (int p = 0; p < 16; ++p) {
        int kk = p * 4 + kb;
        float v = src[(k0 + kk) * 256 + hbase + hh];
        if (spart) v = sqrtf(fmaxf(v, 0.0f) + 1e-6f);
        T[kk][hh] = bf16b(v);
    }
    __syncthreads();

    const int cc = t >> 2, kq = t & 3;
    short8 lo, hi;
    #pragma unroll
    for (int j = 0; j < 8; ++j) lo[j] = (short)T[kq * 16 + j][cc];
    #pragma unroll
    for (int j = 0; j < 8; ++j) hi[j] = (short)T[kq * 16 + 8 + j][cc];

    const int cR = c0 + cc;
    const int g1 = (k0 >> 3) + 2 * kq;                   // global 16B-chunk 0..63
    const int g2 = g1 + 1;
    const int d1 = (g1 >> 3) * 4096 + cR * 8 + ((g1 & 7) ^ (cR & 7));
    const int d2 = (g2 >> 3) * 4096 + cR * 8 + ((g2 & 7) ^ (cR & 7));
    short* wb = (short*)wcbt;
    *(short8*)(wb + d1 * 8) = lo;
    *(short8*)(wb + d2 * 8) = hi;
}

// ------------------------------------------------------------------ main ----
// 256 blocks x 512 threads (1 block/CU). Block (r = bid>>2, q = bid&3) owns
// rows [r*64, +64) x 128 cols: m-cols h in [q*64,+64) AND matching s-cols.
// B streamed in 8 chunks of [128 c][64 k] (16 KB) double-buffered (identity
// copy from pre-swizzled wcbt); A panel 64x512 (64 KB) staged once.
// LDS = 2*16K + 64K = 96 KB. Streamed traffic 65.6 MB (vs 97.6 in R12).
// Wave: rows (w&3)*16, col pair cw = w>>2. Pred partials combined across the
// 4 col-quarters via unsafeAtomicAdd (out pre-zeroed in prep).
__global__ __launch_bounds__(512) void main_kernel(
    const __hip_bfloat16* __restrict__ wcbt, const float* __restrict__ params,
    const float* __restrict__ x, const float* __restrict__ W1,
    const float* __restrict__ eps, float* __restrict__ out)
{
    extern __shared__ char smem[];
    char*  Ap = smem + 32768;                            // [64 r][512 k] bf16
    float* Cl = (float*)smem;                            // [128 lc][68] (alias B+A)

    const int t = threadIdx.x;
    const int w = t >> 6, lane = t & 63;
    const int lane15 = lane & 15, quad = lane >> 4;
    const int ax7 = lane15 & 7;
    const int q  = blockIdx.x & 3;                       // col quarter
    const int bm = (blockIdx.x >> 2) * 64;               // row base

    const char* wbase = (const char*)wcbt;

    // ---- B staging mapping: local chunk j in [0,1024): lc=j>>3, g=j&7.
    //      IDENTITY within the column (swizzle stays baked in).
    int bsrc_c0, bsrc_c1;
    {
        int j0 = t, j1 = 512 + t;
        int lc0 = j0 >> 3, g0 = j0 & 7;
        int lc1 = j1 >> 3, g1 = j1 & 7;
        int cg0 = q * 64 + (lc0 & 63) + ((lc0 >> 6) * 256);
        int cg1 = q * 64 + (lc1 & 63) + ((lc1 >> 6) * 256);
        bsrc_c0 = cg0 * 8 + g0;
        bsrc_c1 = cg1 * 8 + g1;
    }

    // ---- issue B chunk 0 staging (2 x 16B per thread, identity copy)
    gl_lds16(wbase + bsrc_c0 * 16, smem + t * 16);
    gl_lds16(wbase + bsrc_c1 * 16, smem + (512 + t) * 16);

    // ---- A panel staging: thread -> row t>>3, segs (t&7) + ss*8 (4 passes)
    {
        const int r = t >> 3, seg0 = t & 7;
        const float* xrow = x + (bm + r) * D_P1;
        #pragma unroll
        for (int ss = 0; ss < 4; ++ss) {
            const int seg = seg0 + ss * 8;               // 16-elem segment 0..31
            #pragma unroll
            for (int c2 = 0; c2 < 2; ++c2) {
                int g  = seg * 2 + c2;
                int cs = (g & ~7) | ((g & 7) ^ (r & 7));
                short8 pk;
                #pragma unroll
                for (int j = 0; j < 8; ++j)
                    pk[j] = (short)bf16b(xrow[seg * 16 + c2 * 8 + j]);
                *(short8*)(Ap + r * 1024 + cs * 16) = pk;
            }
        }
    }

    // ---- early independent loads (k=512 fixup, eps, wl)
    const float e = eps[lane];
    const int rh = w & 3;                                // row group (16 rows)
    const int cw = w >> 2;                               // col half 0..1
    float xl[4];
    #pragma unroll
    for (int i = 0; i < 4; ++i)
        xl[i] = x[(bm + rh * 16 + quad * 4 + i) * D_P1 + 512];
    float wlm[2], wls[2];
    #pragma unroll
    for (int s = 0; s < 2; ++s) {
        int gc = q * 64 + cw * 32 + s * 16 + lane15;     // m col (h index)
        wlm[s] = params[131072 + gc];
        wls[s] = sqrtf(fmaxf(params[LEN_M + 131072 + gc], 0.0f) + 1e-6f);
    }

    // ---- B fragment byte bases: m-cols lc = cw*32+s*16+lane15; s-cols +64
    int cbm[2], cbs[2];
    #pragma unroll
    for (int s = 0; s < 2; ++s) {
        int lc = cw * 32 + s * 16 + lane15;
        cbm[s] = lc * 128;
        cbs[s] = (lc + 64) * 128;
    }
    const char* Abase = Ap + (rh * 16 + lane15) * 1024;

    floatx4 am0 = {0.f,0.f,0.f,0.f}, am1 = am0, as0 = am0, as1 = am0;

    __syncthreads();                                     // A + B chunk 0 ready

    for (int kc = 0; kc < 8; ++kc) {
        if (kc < 7) {                                    // prefetch next chunk
            char* nbuf = smem + ((kc + 1) & 1) * 16384;
            const char* src = wbase + (kc + 1) * 65536;
            gl_lds16(src + bsrc_c0 * 16, nbuf + t * 16);
            gl_lds16(src + bsrc_c1 * 16, nbuf + (512 + t) * 16);
        }
        const char* Bb = smem + (kc & 1) * 16384;
        const char* Ab = Abase + kc * 128;
        #pragma unroll
        for (int kk = 0; kk < 2; ++kk) {
            const int off = ((kk * 4 + quad) ^ ax7) * 16;
            short8 a  = *(const short8*)(Ab + off);
            short8 b0 = *(const short8*)(Bb + cbm[0] + off);
            short8 b1 = *(const short8*)(Bb + cbm[1] + off);
            short8 b2 = *(const short8*)(Bb + cbs[0] + off);
            short8 b3 = *(const short8*)(Bb + cbs[1] + off);
            am0 = __builtin_amdgcn_mfma_f32_16x16x32_bf16(a, b0, am0, 0, 0, 0);
            am1 = __builtin_amdgcn_mfma_f32_16x16x32_bf16(a, b1, am1, 0, 0, 0);
            as0 = __builtin_amdgcn_mfma_f32_16x16x32_bf16(a, b2, as0, 0, 0, 0);
            as1 = __builtin_amdgcn_mfma_f32_16x16x32_bf16(a, b3, as1, 0, 0, 0);
        }
        __syncthreads();                                 // prefetch drained
    }

    // ---- fixup k=512 + C -> LDS [lc][68] (aliases B + dead A)
    {
        const int r0 = rh * 16 + quad * 4;
        floatx4 accm[2] = {am0, am1}, accs[2] = {as0, as1};
        #pragma unroll
        for (int s = 0; s < 2; ++s) {
            float4 om, os;
            om.x = accm[s][0] + xl[0] * wlm[s];  os.x = accs[s][0] + xl[0] * wls[s];
            om.y = accm[s][1] + xl[1] * wlm[s];  os.y = accs[s][1] + xl[1] * wls[s];
            om.z = accm[s][2] + xl[2] * wlm[s];  os.z = accs[s][2] + xl[2] * wls[s];
            om.w = accm[s][3] + xl[3] * wlm[s];  os.w = accs[s][3] + xl[3] * wls[s];
            const int lc = cw * 32 + s * 16 + lane15;
            *(float4*)&Cl[lc * 68 + r0]        = om;
            *(float4*)&Cl[(64 + lc) * 68 + r0] = os;
        }
    }
    __syncthreads();

    // ---- pred epilogue: lane = m; wave w rows w*8..w*8+7; 64 local h's
    const int rw = w * 8;
    v2f accp0 = {0.f,0.f}, accp1 = accp0, accp2 = accp0, accp3 = accp0;
    const v2f e2 = {e, e}, z2 = {0.f, 0.f};

    #pragma unroll 8
    for (int hh = 0; hh < 64; ++hh) {
        const float w1h = W1[1 + q * 64 + hh];
        const v2f w2 = {w1h, w1h};
        const float4 av0 = *(const float4*)&Cl[hh * 68 + rw];
        const float4 av1 = *(const float4*)&Cl[hh * 68 + rw + 4];
        const float4 bv0 = *(const float4*)&Cl[(64 + hh) * 68 + rw];
        const float4 bv1 = *(const float4*)&Cl[(64 + hh) * 68 + rw + 4];
        v2f t0 = __builtin_elementwise_max(
                     __builtin_elementwise_fma(e2, (v2f){bv0.x, bv0.y}, (v2f){av0.x, av0.y}), z2);
        v2f t1 = __builtin_elementwise_max(
                     __builtin_elementwise_fma(e2, (v2f){bv0.z, bv0.w}, (v2f){av0.z, av0.w}), z2);
        v2f t2 = __builtin_elementwise_max(
                     __builtin_elementwise_fma(e2, (v2f){bv1.x, bv1.y}, (v2f){av1.x, av1.y}), z2);
        v2f t3 = __builtin_elementwise_max(
                     __builtin_elementwise_fma(e2, (v2f){bv1.z, bv1.w}, (v2f){av1.z, av1.w}), z2);
        accp0 = __builtin_elementwise_fma(t0, w2, accp0);
        accp1 = __builtin_elementwise_fma(t1, w2, accp1);
        accp2 = __builtin_elementwise_fma(t2, w2, accp2);
        accp3 = __builtin_elementwise_fma(t3, w2, accp3);
    }
    if (q == 0) {
        const float b0 = W1[0];
        accp0.x += b0; accp0.y += b0; accp1.x += b0; accp1.y += b0;
        accp2.x += b0; accp2.y += b0; accp3.x += b0; accp3.y += b0;
    }

    float* op = out + (bm + rw) * 64 + lane;
    unsafeAtomicAdd(op,       accp0.x);
    unsafeAtomicAdd(op + 64,  accp0.y);
    unsafeAtomicAdd(op + 128, accp1.x);
    unsafeAtomicAdd(op + 192, accp1.y);
    unsafeAtomicAdd(op + 256, accp2.x);
    unsafeAtomicAdd(op + 320, accp2.y);
    unsafeAtomicAdd(op + 384, accp3.x);
    unsafeAtomicAdd(op + 448, accp3.y);
}

// -------------------------------------------------------------- launch ------
extern "C" void kernel_launch(void* const* d_in, const int* in_sizes, int n_in,
                              void* d_out, int out_size, void* d_ws, size_t ws_size,
                              hipStream_t stream)
{
    const float* params = (const float*)d_in[0];
    const float* W1     = (const float*)d_in[1];
    const float* x      = (const float*)d_in[2];
    const float* eps    = (const float*)d_in[3];
    float* out = (float*)d_out;
    __hip_bfloat16* wcbt = (__hip_bfloat16*)d_ws;

    static bool attr_set = false;
    if (!attr_set) {
        hipFuncSetAttribute((const void*)main_kernel,
                            hipFuncAttributeMaxDynamicSharedMemorySize, 98304);
        attr_set = true;
    }

    prep_kernel<<<833, 256, 0, stream>>>(params, out, wcbt);
    main_kernel<<<256, 512, 98304, stream>>>(wcbt, params, x, W1, eps, out);
}

// Round 14
// 82.393 us; speedup vs baseline: 1.0254x; 1.0254x over previous
//
#include <hip/hip_runtime.h>
#include <hip/hip_bf16.h>
#include <math.h>

#define LEN_M   131328
#define D_P1    513
#define NROW    4096
#define PRED_ELEMS (NROW * 64)            // 262144

// ws: wcbt bf16, 512 KB: 8 k-chunks (kc) of 64 KB; each holds all 512 cols x
// 64 k as 16B chunks, swizzled: chunk_idx(c, g, kc) = kc*4096 + c*8 + (g^(c&7))
typedef __attribute__((ext_vector_type(8))) short short8;     // 8 bf16 = 4 VGPR
typedef __attribute__((ext_vector_type(4))) float floatx4;    // mfma acc
typedef __attribute__((ext_vector_type(2))) float v2f;        // packed fp32

__device__ __forceinline__ void gl_lds16(const void* g, void* l)
{
    __builtin_amdgcn_global_load_lds(
        (const __attribute__((address_space(1))) unsigned int*)g,
        (__attribute__((address_space(3))) unsigned int*)l, 16, 0, 0);
}

__device__ __forceinline__ unsigned short bf16b(float f)
{
    __hip_bfloat16 h = __float2bfloat16(f);
    return *(unsigned short*)&h;
}

// ------------------------------------------------------------------ prep ----
// blocks [0,513): m_w0 / v_w0 outputs (513*256 == LEN_M exactly)
// blocks [513,769): zero pred region (atomic accumulation base)
// blocks [769,833): build swizzled wcbt via LDS transpose
__global__ __launch_bounds__(256) void prep_kernel(
    const float* __restrict__ params, float* __restrict__ out,
    __hip_bfloat16* __restrict__ wcbt)
{
    __shared__ unsigned short T[64][65];
    const int bid = blockIdx.x;
    const int t   = threadIdx.x;

    if (bid < 513) {
        int i = bid * 256 + t;
        float m = params[i];
        float v = fmaxf(params[LEN_M + i], 0.0f) + 1e-6f;
        out[PRED_ELEMS + i]         = m;                 // m_w0
        out[PRED_ELEMS + LEN_M + i] = v;                 // v_w0
        return;
    }
    if (bid < 769) {
        int i = (bid - 513) * 1024 + t * 4;
        float4 z = {0.f, 0.f, 0.f, 0.f};
        *(float4*)(out + i) = z;
        return;
    }

    const int b2 = bid - 769;
    const int k0 = (b2 & 7) * 64;
    const int c0 = (b2 >> 3) * 64;
    const int hh = t & 63, kb = t >> 6;
    const bool spart = (c0 >= 256);
    const int hbase = c0 & 255;
    const float* src = params + (spart ? LEN_M : 0);

    #pragma unroll 4
    for (int p = 0; p < 16; ++p) {
        int kk = p * 4 + kb;
        float v = src[(k0 + kk) * 256 + hbase + hh];
        if (spart) v = sqrtf(fmaxf(v, 0.0f) + 1e-6f);
        T[kk][hh] = bf16b(v);
    }
    __syncthreads();

    const int cc = t >> 2, kq = t & 3;
    short8 lo, hi;
    #pragma unroll
    for (int j = 0; j < 8; ++j) lo[j] = (short)T[kq * 16 + j][cc];
    #pragma unroll
    for (int j = 0; j < 8; ++j) hi[j] = (short)T[kq * 16 + 8 + j][cc];

    const int cR = c0 + cc;
    const int g1 = (k0 >> 3) + 2 * kq;                   // global 16B-chunk 0..63
    const int g2 = g1 + 1;
    const int d1 = (g1 >> 3) * 4096 + cR * 8 + ((g1 & 7) ^ (cR & 7));
    const int d2 = (g2 >> 3) * 4096 + cR * 8 + ((g2 & 7) ^ (cR & 7));
    short* wb = (short*)wcbt;
    *(short8*)(wb + d1 * 8) = lo;
    *(short8*)(wb + d2 * 8) = hi;
}

// ------------------------------------------------------------------ main ----
// 512 blocks x 512 threads. Block (r = bid>>2, q = bid&3) owns rows
// [r*32, +32) x 128 cols: m-cols h in [q*64,+64) AND matching s-cols.
// B streamed in 8 chunks of [128 c][64 k] (16 KB) double-buffered from the
// pre-swizzled wcbt (IDENTITY copy — swizzle preserved); A panel 32x512
// staged once. LDS = 2*16K + 32K = 64 KB -> 2 blocks/CU (empirically optimal:
// R10 more-traffic/2-per-CU and R13 less-traffic/1-per-CU both regress).
// Pred partials combined across col-quarters via unsafeAtomicAdd.
__global__ __launch_bounds__(512) void main_kernel(
    const __hip_bfloat16* __restrict__ wcbt, const float* __restrict__ params,
    const float* __restrict__ x, const float* __restrict__ W1,
    const float* __restrict__ eps, float* __restrict__ out)
{
    extern __shared__ char smem[];
    char*  Ap = smem + 32768;                            // [32 r][512 k] bf16
    float* Cl = (float*)smem;                            // [128 lc][36] (alias B)

    const int t = threadIdx.x;
    const int w = t >> 6, lane = t & 63;
    const int lane15 = lane & 15, quad = lane >> 4;
    const int ax7 = lane15 & 7;
    const int q  = blockIdx.x & 3;                       // col quarter
    const int bm = (blockIdx.x >> 2) * 32;               // row base

    const char* wbase = (const char*)wcbt;

    // ---- B staging mapping: local chunk j in [0,1024): lc=j>>3, g=j&7.
    //      IDENTITY within the column (swizzle stays baked in):
    //      src = cglob*8 + g,  cglob = q*64 + (lc&63) + (lc>=64)*256
    int bsrc_c0, bsrc_c1;
    {
        int j0 = t, j1 = 512 + t;
        int lc0 = j0 >> 3, g0 = j0 & 7;
        int lc1 = j1 >> 3, g1 = j1 & 7;
        int cg0 = q * 64 + (lc0 & 63) + ((lc0 >> 6) * 256);
        int cg1 = q * 64 + (lc1 & 63) + ((lc1 >> 6) * 256);
        bsrc_c0 = cg0 * 8 + g0;
        bsrc_c1 = cg1 * 8 + g1;
    }

    // ---- issue B chunk 0 staging (2 x 16B per thread, identity copy)
    gl_lds16(wbase + bsrc_c0 * 16, smem + t * 16);
    gl_lds16(wbase + bsrc_c1 * 16, smem + (512 + t) * 16);

    // ---- A panel staging: thread -> row t>>4, segs (t&15) and (t&15)+16
    {
        const int r = t >> 4, seg0 = t & 15;
        const float* xrow = x + (bm + r) * D_P1;
        #pragma unroll
        for (int ss = 0; ss < 2; ++ss) {
            const int seg = seg0 + ss * 16;
            #pragma unroll
            for (int c2 = 0; c2 < 2; ++c2) {
                int g  = seg * 2 + c2;
                int cs = (g & ~7) | ((g & 7) ^ (r & 7));
                short8 pk;
                #pragma unroll
                for (int j = 0; j < 8; ++j)
                    pk[j] = (short)bf16b(xrow[seg * 16 + c2 * 8 + j]);
                *(short8*)(Ap + r * 1024 + cs * 16) = pk;
            }
        }
    }

    // ---- early independent loads (k=512 fixup, eps, wl)
    const float e = eps[lane];
    const int rh = w & 1;                                // row half (16 rows)
    const int ct = w >> 1;                               // col tile 0..3
    float xl[4];
    #pragma unroll
    for (int i = 0; i < 4; ++i)
        xl[i] = x[(bm + rh * 16 + quad * 4 + i) * D_P1 + 512];
    const int gc0 = q * 64 + ct * 16 + lane15;           // m col
    const float wl0 = params[131072 + gc0];
    const float wl1 = sqrtf(fmaxf(params[LEN_M + 131072 + gc0], 0.0f) + 1e-6f);

    const int cb0 = (ct * 16 + lane15) * 128;            // B frag byte bases
    const int cb1 = cb0 + 64 * 128;
    const char* Abase = Ap + (rh * 16 + lane15) * 1024;

    floatx4 acc0 = {0.f,0.f,0.f,0.f}, acc1 = acc0;

    __syncthreads();                                     // A + B chunk 0 ready

    for (int kc = 0; kc < 8; ++kc) {
        if (kc < 7) {                                    // prefetch next chunk
            char* nbuf = smem + ((kc + 1) & 1) * 16384;
            const char* src = wbase + (kc + 1) * 65536;
            gl_lds16(src + bsrc_c0 * 16, nbuf + t * 16);
            gl_lds16(src + bsrc_c1 * 16, nbuf + (512 + t) * 16);
        }
        const char* Bb = smem + (kc & 1) * 16384;
        const char* Ab = Abase + kc * 128;
        #pragma unroll
        for (int kk = 0; kk < 2; ++kk) {
            const int off = ((kk * 4 + quad) ^ ax7) * 16;
            short8 a  = *(const short8*)(Ab + off);
            short8 b0 = *(const short8*)(Bb + cb0 + off);
            short8 b1 = *(const short8*)(Bb + cb1 + off);
            acc0 = __builtin_amdgcn_mfma_f32_16x16x32_bf16(a, b0, acc0, 0, 0, 0);
            acc1 = __builtin_amdgcn_mfma_f32_16x16x32_bf16(a, b1, acc1, 0, 0, 0);
        }
        __syncthreads();                                 // prefetch drained
    }

    // ---- fixup k=512 + C -> LDS [lc][36] (aliases B; all B reads done)
    {
        const int r0 = rh * 16 + quad * 4;
        float4 o0, o1;
        o0.x = acc0[0] + xl[0] * wl0;  o1.x = acc1[0] + xl[0] * wl1;
        o0.y = acc0[1] + xl[1] * wl0;  o1.y = acc1[1] + xl[1] * wl1;
        o0.z = acc0[2] + xl[2] * wl0;  o1.z = acc1[2] + xl[2] * wl1;
        o0.w = acc0[3] + xl[3] * wl0;  o1.w = acc1[3] + xl[3] * wl1;
        *(float4*)&Cl[(ct * 16 + lane15) * 36 + r0]      = o0;
        *(float4*)&Cl[(64 + ct * 16 + lane15) * 36 + r0] = o1;
    }
    __syncthreads();

    // ---- pred epilogue: lane = m; wave w rows w*4..w*4+3; 64 local h's
    const int rw = w * 4;
    v2f accp0 = {0.f, 0.f}, accp1 = {0.f, 0.f};
    const v2f e2 = {e, e}, z2 = {0.f, 0.f};

    #pragma unroll 8
    for (int hh = 0; hh < 64; ++hh) {
        const float w1h = W1[1 + q * 64 + hh];
        const v2f w2 = {w1h, w1h};
        const float4 av = *(const float4*)&Cl[hh * 36 + rw];         // m-part
        const float4 bv = *(const float4*)&Cl[(64 + hh) * 36 + rw];  // s-part
        v2f a01 = {av.x, av.y}, a23 = {av.z, av.w};
        v2f b01 = {bv.x, bv.y}, b23 = {bv.z, bv.w};
        v2f t01 = __builtin_elementwise_max(__builtin_elementwise_fma(e2, b01, a01), z2);
        v2f t23 = __builtin_elementwise_max(__builtin_elementwise_fma(e2, b23, a23), z2);
        accp0 = __builtin_elementwise_fma(t01, w2, accp0);
        accp1 = __builtin_elementwise_fma(t23, w2, accp1);
    }
    if (q == 0) {
        const float b0 = W1[0];
        accp0.x += b0; accp0.y += b0; accp1.x += b0; accp1.y += b0;
    }

    float* op = out + (bm + rw) * 64 + lane;
    unsafeAtomicAdd(op,       accp0.x);
    unsafeAtomicAdd(op + 64,  accp0.y);
    unsafeAtomicAdd(op + 128, accp1.x);
    unsafeAtomicAdd(op + 192, accp1.y);
}

// -------------------------------------------------------------- launch ------
extern "C" void kernel_launch(void* const* d_in, const int* in_sizes, int n_in,
                              void* d_out, int out_size, void* d_ws, size_t ws_size,
                              hipStream_t stream)
{
    const float* params = (const float*)d_in[0];
    const float* W1     = (const float*)d_in[1];
    const float* x      = (const float*)d_in[2];
    const float* eps    = (const float*)d_in[3];
    float* out = (float*)d_out;
    __hip_bfloat16* wcbt = (__hip_bfloat16*)d_ws;

    static bool attr_set = false;
    if (!attr_set) {
        hipFuncSetAttribute((const void*)main_kernel,
                            hipFuncAttributeMaxDynamicSharedMemorySize, 65536);
        attr_set = true;
    }

    prep_kernel<<<833, 256, 0, stream>>>(params, out, wcbt);
    main_kernel<<<512, 512, 65536, stream>>>(wcbt, params, x, W1, eps, out);
}